// Round 19
// baseline (61.180 us; speedup 1.0000x reference)
//
#include <hip/hip_runtime.h>

// Problem constants
#define DMODEL 256
#define HEADS 8
#define DHEAD 32
#define NSEQ 2048
#define BATCH 4
#define MTOT (BATCH*NSEQ)   // 8192

typedef __bf16 bf16x8 __attribute__((ext_vector_type(8)));
typedef float f32x4 __attribute__((ext_vector_type(4)));

// scale * log2(e) * 128: softmax_2(s*CS) computed via Schraudolph int exp2
// (bits16(2^y) ~= y + 16252 for y = s*CS*128; bias folded into QK MFMA C-in)
#define CSH 32.649321103346387f
// Schraudolph bias: 127<<7 = 16256, minus sigma 4.5 (minmax), plus 0.5 trunc
#define EXPC 16252.0f

__device__ __forceinline__ unsigned short f2bf(float f) {
    union { float f; unsigned int u; } v; v.f = f;
    unsigned int u = v.u;
    unsigned int r = u + 0x7FFFu + ((u >> 16) & 1u);   // RNE
    return (unsigned short)(r >> 16);
}

__device__ __forceinline__ unsigned pkbf(float a, float b) {
    union { __bf16 h[2]; unsigned u; } t;
    t.h[0] = (__bf16)a; t.h[1] = (__bf16)b;
    return t.u;
}

// packed Schraudolph exp2 finish: inputs already = score + EXPC (bias folded
// into the QK MFMA accumulator init). 2x v_cvt_i32_f32 + 1x v_perm_b32.
__device__ __forceinline__ unsigned pkexp(float a, float b) {
    int ia = (int)a;
    int ib = (int)b;
    return __builtin_amdgcn_perm((unsigned)ib, (unsigned)ia, 0x05040100u);
}

__device__ __forceinline__ f32x4 mfma16(bf16x8 a, bf16x8 b, f32x4 c) {
    return __builtin_amdgcn_mfma_f32_16x16x32_bf16(a, b, c, 0, 0, 0);
}

#define GLD16(g, l) __builtin_amdgcn_global_load_lds( \
    (const __attribute__((address_space(1))) unsigned int*)(g), \
    (__attribute__((address_space(3))) unsigned int*)(l), 16, 0, 0)

// ---------------------------------------------------------------------------
// prep (2390 blocks):
//  blocks 0..256    : Woc = Wo@Wc fold (row 256 = boc = bo@Wc + bc)
//  blocks 257..2304 : x -> bf16 (coalesced float4 -> ushort4)
//  blocks 2305..2384: tiled-coalesced weight transpose -> Wt[n][k] bf16
//  blocks 2385..2389: bias concat
// ---------------------------------------------------------------------------
__global__ __launch_bounds__(256) void prep_kernel(
    const float* __restrict__ x,
    const float* __restrict__ Wq, const float* __restrict__ Wk,
    const float* __restrict__ Wv, const float* __restrict__ Wo,
    const float* __restrict__ Wc,
    const float* __restrict__ bq, const float* __restrict__ bk,
    const float* __restrict__ bv, const float* __restrict__ bo,
    const float* __restrict__ bc,
    unsigned short* __restrict__ xbf,   // [8192][256]
    unsigned short* __restrict__ Wt,    // [1280][256]
    float* __restrict__ bcat,           // [1280]
    unsigned short* __restrict__ Woct,  // [256][256] = Woc^T bf16
    float* __restrict__ bocf)           // [256]
{
    const int tid = threadIdx.x;
    if (blockIdx.x < 257) {             // Woc / boc fold
        int k = blockIdx.x;             // 0..256
        int n = tid;                    // 0..255
        const float* arow = (k < 256) ? (Wo + k * 256) : bo;
        float a0 = 0.f, a1 = 0.f, a2 = 0.f, a3 = 0.f;
#pragma unroll 4
        for (int j = 0; j < 256; j += 4) {
            a0 = fmaf(arow[j],     Wc[j * 256 + n],       a0);
            a1 = fmaf(arow[j + 1], Wc[(j + 1) * 256 + n], a1);
            a2 = fmaf(arow[j + 2], Wc[(j + 2) * 256 + n], a2);
            a3 = fmaf(arow[j + 3], Wc[(j + 3) * 256 + n], a3);
        }
        float acc = (a0 + a1) + (a2 + a3);
        if (k < 256) Woct[n * 256 + k] = f2bf(acc);
        else         bocf[n] = acc + bc[n];
        return;
    }
    if (blockIdx.x < 2305) {            // x -> bf16
        int idx = (blockIdx.x - 257) * 256 + tid;     // < 524288
        float4 v = reinterpret_cast<const float4*>(x)[idx];
        ushort4 o;
        o.x = f2bf(v.x); o.y = f2bf(v.y); o.z = f2bf(v.z); o.w = f2bf(v.w);
        reinterpret_cast<ushort4*>(xbf)[idx] = o;
        return;
    }
    if (blockIdx.x < 2385) {            // transpose: 64n x 64k tile
        __shared__ unsigned short Lt[64 * 72];
        const int bb = blockIdx.x - 2305;
        const int wid = tid >> 6, lane = tid & 63;
        const int n0 = (bb >> 2) * 64, k0 = (bb & 3) * 64;
        const float* Wsrc; int col0;
        if (n0 < 256)       { Wsrc = Wq; col0 = n0; }
        else if (n0 < 512)  { Wsrc = Wk; col0 = n0 - 256; }
        else if (n0 < 768)  { Wsrc = Wv; col0 = n0 - 512; }
        else if (n0 < 1024) { Wsrc = Wo; col0 = n0 - 768; }
        else                { Wsrc = Wc; col0 = n0 - 1024; }
#pragma unroll
        for (int r = 0; r < 16; ++r) {
            int k = k0 + wid * 16 + r;
            Lt[lane * 72 + wid * 16 + r] = f2bf(Wsrc[k * 256 + col0 + lane]);
        }
        __syncthreads();
#pragma unroll
        for (int c = tid; c < 512; c += 256) {
            int row = c >> 3, seg = c & 7;
            *reinterpret_cast<bf16x8*>(Wt + (n0 + row) * 256 + k0 + seg * 8) =
                *reinterpret_cast<const bf16x8*>(Lt + row * 72 + seg * 8);
        }
        return;
    }
    int t = (blockIdx.x - 2385) * 256 + tid;   // bias concat
    if (t < 1280) {
        float v;
        if (t < 256)       v = bq[t];
        else if (t < 512)  v = bk[t - 256];
        else if (t < 768)  v = bv[t - 512];
        else if (t < 1024) v = bo[t - 768];
        else               v = bc[t - 1024];
        bcat[t] = v;
    }
}

// ---------------------------------------------------------------------------
// gemm_qkv: A = xbf (bf16). Wt staged in LDS (XOR-swizzled via pre-swizzled
// global_load_lds source). 32x64 per wave. LDS-bounce epilogue (b128 stores):
//   type 0/1 (Q/K): [128 m][72]; Q pre-scaled by CSH (= CS*128, Schraudolph).
//   type 2 (V): transposed [64 gc][136], stored KEY-PERMUTED:
//     pos0 = (nn&~63)|(nn&32)|((nn&8)<<1)|((nn&16)>>2) (two 8B writes).
// ---------------------------------------------------------------------------
__global__ __launch_bounds__(256) void gemm_qkv(
    const unsigned short* __restrict__ A,
    const unsigned short* __restrict__ Wt,
    const float* __restrict__ bias,
    unsigned short* __restrict__ outQ,
    unsigned short* __restrict__ outK,
    unsigned short* __restrict__ outVt)
{
    __shared__ __align__(16) unsigned short Bl[64 * 256];   // 32 KB
    const int tid = threadIdx.x;
    const int wid = tid >> 6;
    const int lane = tid & 63;
    const int lo = lane & 15, hi = lane >> 4;
    const int m0 = blockIdx.x * 128 + wid * 32;
    const int n0 = blockIdx.y * 64;

#pragma unroll
    for (int j = 0; j < 8; ++j) {
        int chunkbase = (j * 4 + wid) * 64;
        int chunk = chunkbase + lane;
        int row = chunk >> 5, Jp = chunk & 31;
        int J = (Jp & 24) | ((Jp ^ row) & 7);
        GLD16(Wt + (n0 + row) * 256 + J * 8, Bl + chunkbase * 8);
    }
    asm volatile("s_waitcnt vmcnt(0)" ::: "memory");
    __syncthreads();

    const unsigned short* arow0 = A + (m0 + lo) * 256 + hi * 8;
    f32x4 acc[2][4] = {};
#pragma unroll
    for (int s = 0; s < 8; ++s) {
        bf16x8 a0 = *reinterpret_cast<const bf16x8*>(arow0 + s * 32);
        bf16x8 a1 = *reinterpret_cast<const bf16x8*>(arow0 + 16 * 256 + s * 32);
        int Jp = ((s >> 1) << 3) | ((((s & 1) << 2) + hi) ^ (lo & 7));
#pragma unroll
        for (int n = 0; n < 4; ++n) {
            bf16x8 b = *reinterpret_cast<const bf16x8*>(
                Bl + (n * 16 + lo) * 256 + Jp * 8);
            acc[0][n] = mfma16(a0, b, acc[0][n]);
            acc[1][n] = mfma16(a1, b, acc[1][n]);
        }
    }

    // LDS-bounce epilogue
    const int type = blockIdx.y >> 2;     // 0:Q 1:K 2:V
    const int m0b = blockIdx.x * 128;
    unsigned short* Lb = Bl;
    __syncthreads();
    if (type < 2) {                       // [128][72]
#pragma unroll
        for (int mf = 0; mf < 2; ++mf)
#pragma unroll
        for (int n = 0; n < 4; ++n) {
            float bs = bias[n0 + n * 16 + lo];
#pragma unroll
            for (int i = 0; i < 4; ++i) {
                float val = acc[mf][n][i] + bs;
                if (type == 0) val *= CSH;
                Lb[(wid * 32 + mf * 16 + hi * 4 + i) * 72 + n * 16 + lo] = f2bf(val);
            }
        }
    } else {                              // transposed [64][136]
#pragma unroll
        for (int mf = 0; mf < 2; ++mf)
#pragma unroll
        for (int n = 0; n < 4; ++n) {
            float bs = bias[n0 + n * 16 + lo];
            uint2 pk;
            pk.x = pkbf(acc[mf][n][0] + bs, acc[mf][n][1] + bs);
            pk.y = pkbf(acc[mf][n][2] + bs, acc[mf][n][3] + bs);
            *reinterpret_cast<uint2*>(
                Lb + (n * 16 + lo) * 136 + wid * 32 + mf * 16 + hi * 4) = pk;
        }
    }
    __syncthreads();
    if (type < 2) {
        unsigned short* outP = (type == 0) ? outQ : outK;
#pragma unroll
        for (int r = 0; r < 4; ++r) {
            int cid = r * 256 + tid;
            int m_l = cid >> 3, seg = cid & 7;
            bf16x8 chunk = *reinterpret_cast<const bf16x8*>(Lb + m_l * 72 + seg * 8);
            int m = m0b + m_l, gc = n0 + seg * 8;
            int b = m >> 11, nn = m & 2047, hh = (gc >> 5) & 7, dh = gc & 31;
            *reinterpret_cast<bf16x8*>(
                outP + (((b * 8) + hh) * 2048 + nn) * 32 + dh) = chunk;
        }
    } else {
#pragma unroll
        for (int r = 0; r < 4; ++r) {
            int cid = r * 256 + tid;
            int gcl = cid >> 4, seg = cid & 15;
            const unsigned short* src = Lb + gcl * 136 + seg * 8;
            uint2 lo4 = *reinterpret_cast<const uint2*>(src);
            uint2 hi4 = *reinterpret_cast<const uint2*>(src + 4);
            int gc = n0 + gcl, m = m0b + seg * 8;
            int b = m >> 11, nn = m & 2047, hh = (gc >> 5) & 7, dh = gc & 31;
            int pos0 = (nn & ~63) | (nn & 32) | ((nn & 8) << 1) | ((nn & 16) >> 2);
            unsigned short* dst = outVt + (((b * 8) + hh) * 32 + dh) * 2048;
            *reinterpret_cast<uint2*>(dst + pos0)     = lo4;
            *reinterpret_cast<uint2*>(dst + pos0 + 8) = hi4;
        }
    }
}

// ---------------------------------------------------------------------------
// Flash attention v14: KVBLK=64, 32 KB LDS -> 4 blocks/CU (4 independent
// barrier domains, 16 waves/CU) — attacks the 2-phase stall (m233).
// 64 q-rows/wave in 4 groups; split-KV (2 qsub x 2 half); 16 x 64-key
// double-buffered tiles. Schraudolph bias in QK MFMA C-in; softmax finish
// = 2x cvt + 1x perm per 2 scores. Lane-local PV B-frags (V key-permuted);
// denom via ones-MFMA. Halves combined via 24 KB LDS (pure addition).
// ---------------------------------------------------------------------------
__global__ __launch_bounds__(256, 4) void attn_kernel(
    const unsigned short* __restrict__ Q,    // [32][2048][32] bf16 (pre-scaled CSH)
    const unsigned short* __restrict__ K,    // [32][2048][32] bf16
    const unsigned short* __restrict__ Vt,   // [32][32][2048] bf16 (permuted)
    unsigned short* __restrict__ ctx)        // [8192][256] bf16 (heads merged)
{
    // K: [half][buf] @ half*8192 + buf*4096 ; V same @ +16384. 32 KB.
    __shared__ __align__(16) char smem[32768];

    const int tid = threadIdx.x;
    const int wid = tid >> 6;          // 0..3
    const int lane = tid & 63;
    const int lo = lane & 15, hi = lane >> 4;
    const int qsub = wid & 1;
    const int half = wid >> 1;

    // XCD swizzle: bid = 8*(qt + 16*g) + r ; bh = g*8+r
    const int bid = blockIdx.x;
    const int bh = ((bid >> 7) << 3) | (bid & 7);
    const int qt = (bid >> 3) & 15;
    const int q0 = qt * 128 + qsub * 64;

    const unsigned short* Qb = Q + bh * (NSEQ * 32);
    const unsigned short* Kh0 = K + bh * (NSEQ * 32) + (half * 1024) * 32;
    const unsigned short* Vh0 = Vt + bh * (32 * NSEQ) + half * 1024;

    bf16x8 qf[4];
#pragma unroll
    for (int g = 0; g < 4; ++g)
        qf[g] = *reinterpret_cast<const bf16x8*>(
            Qb + (q0 + g * 16 + lo) * 32 + hi * 8);

    // staging: 128 threads per half, 4 GLD16 per thread per 64-key tile
    const int lt2 = tid & 127;
    const int cA = lt2, cB = lt2 + 128;
    const unsigned short* kA0 = Kh0 + (2 * (cA >> 3) + ((cA >> 2) & 1)) * 32
                                    + ((cA & 3) ^ ((cA >> 3) & 3)) * 8;
    const unsigned short* kA1 = Kh0 + (2 * (cB >> 3) + ((cB >> 2) & 1)) * 32
                                    + ((cB & 3) ^ ((cB >> 3) & 3)) * 8;
    const unsigned short* vA0 = Vh0 + (cA >> 3) * NSEQ
                                    + ((cA & 7) ^ ((cA >> 3) & 7)) * 8;
    const unsigned short* vA1 = Vh0 + (cB >> 3) * NSEQ
                                    + ((cB & 7) ^ ((cB >> 3) & 7)) * 8;
    char* kd0 = smem + half * 8192 + lt2 * 16;
    char* kd1 = kd0 + 2048;
    char* vd0 = smem + 16384 + half * 8192 + lt2 * 16;
    char* vd1 = vd0 + 2048;

    f32x4 o0[4] = {}, o1[4] = {}, od[4] = {};
    const f32x4 ec = {EXPC, EXPC, EXPC, EXPC};   // Schraudolph bias as C-in
    const int prs = lo & 7;
    const int kxor = (hi ^ ((lo >> 1) & 3)) * 8;

    union { unsigned u[4]; bf16x8 v; } ones;
    ones.u[0] = 0x3F803F80u; ones.u[1] = 0x3F803F80u;
    ones.u[2] = 0x3F803F80u; ones.u[3] = 0x3F803F80u;

#define STAGE_T(tt, buf) do { \
    GLD16(kA0 + (tt) * 2048, kd0 + (buf) * 4096); \
    GLD16(kA1 + (tt) * 2048, kd1 + (buf) * 4096); \
    GLD16(vA0 + (tt) * 64,   vd0 + (buf) * 4096); \
    GLD16(vA1 + (tt) * 64,   vd1 + (buf) * 4096); \
} while (0)

    STAGE_T(0, 0);
    asm volatile("s_waitcnt vmcnt(0)" ::: "memory");
    __builtin_amdgcn_s_barrier();
    __builtin_amdgcn_sched_barrier(0);

    int cur = 0;
    for (int t = 0; t < 16; ++t) {
        if (t < 15) STAGE_T(t + 1, cur ^ 1);
        const unsigned short* Kh =
            (const unsigned short*)(smem + half * 8192 + cur * 4096);
        const unsigned short* Vh =
            (const unsigned short*)(smem + 16384 + half * 8192 + cur * 4096);

        __builtin_amdgcn_s_setprio(1);
        f32x4 s[4][4];
#pragma unroll
        for (int c = 0; c < 4; ++c) {
            bf16x8 kf = *reinterpret_cast<const bf16x8*>(
                Kh + (c * 16 + lo) * 32 + kxor);
#pragma unroll
            for (int g = 0; g < 4; ++g)
                s[g][c] = mfma16(kf, qf[g], ec);   // bias folded in
        }
#pragma unroll
        for (int kk = 0; kk < 2; ++kk) {
            int sw = ((4 * kk + hi) ^ prs) * 8;
            bf16x8 a0 = *reinterpret_cast<const bf16x8*>(Vh + lo * 64 + sw);
            bf16x8 a1 = *reinterpret_cast<const bf16x8*>(Vh + (16 + lo) * 64 + sw);
#pragma unroll
            for (int g = 0; g < 4; ++g) {
                const f32x4 s0 = s[g][2 * kk], s1 = s[g][2 * kk + 1];
                union { unsigned u[4]; bf16x8 v; } pb;
                pb.u[0] = pkexp(s0[0], s0[1]);
                pb.u[1] = pkexp(s0[2], s0[3]);
                pb.u[2] = pkexp(s1[0], s1[1]);
                pb.u[3] = pkexp(s1[2], s1[3]);
                o0[g] = mfma16(a0, pb.v, o0[g]);
                o1[g] = mfma16(a1, pb.v, o1[g]);
                od[g] = mfma16(ones.v, pb.v, od[g]);
            }
        }
        __builtin_amdgcn_s_setprio(0);

        if (t < 15) {
            asm volatile("s_waitcnt vmcnt(0)" ::: "memory");
            __builtin_amdgcn_s_barrier();
            __builtin_amdgcn_sched_barrier(0);
            cur ^= 1;
        }
    }

    // combine halves (pure addition; no-max softmax partials)
    float* comb = (float*)smem;                 // [2][64][48] = 24 KB
    const int cidx = (qsub * 64 + lane) * 48;
    __syncthreads();
    if (half) {
#pragma unroll
        for (int g = 0; g < 4; ++g) {
            *reinterpret_cast<f32x4*>(comb + cidx + g * 12)     = o0[g];
            *reinterpret_cast<f32x4*>(comb + cidx + g * 12 + 4) = o1[g];
            comb[cidx + g * 12 + 8] = od[g][0];
        }
    }
    __syncthreads();
    if (!half) {
        const int b = bh >> 3, h = bh & 7;
#pragma unroll
        for (int g = 0; g < 4; ++g) {
            f32x4 p0 = *reinterpret_cast<const f32x4*>(comb + cidx + g * 12);
            f32x4 p1 = *reinterpret_cast<const f32x4*>(comb + cidx + g * 12 + 4);
            float inv = 1.0f / (od[g][0] + comb[cidx + g * 12 + 8]);
            f32x4 r0 = o0[g] + p0, r1 = o1[g] + p1;
            unsigned short* dst = ctx
                + (size_t)((b * 2048 + q0 + g * 16 + lo)) * 256 + h * 32;
            ushort4 w0, w1;
            w0.x = f2bf(r0[0] * inv); w0.y = f2bf(r0[1] * inv);
            w0.z = f2bf(r0[2] * inv); w0.w = f2bf(r0[3] * inv);
            w1.x = f2bf(r1[0] * inv); w1.y = f2bf(r1[1] * inv);
            w1.z = f2bf(r1[2] * inv); w1.w = f2bf(r1[3] * inv);
            *reinterpret_cast<ushort4*>(dst + hi * 4)      = w0;
            *reinterpret_cast<ushort4*>(dst + 16 + hi * 4) = w1;
        }
    }
#undef STAGE_T
}

// ---------------------------------------------------------------------------
// gemm_ctx: out = x + ctx @ Woc + boc. A = ctx bf16 direct; B = Woct staged
// in LDS (swizzled). 32 rows x 64 cols / wave.
// ---------------------------------------------------------------------------
__global__ __launch_bounds__(256) void gemm_ctx(
    const unsigned short* __restrict__ A,
    const unsigned short* __restrict__ Wt,
    const float* __restrict__ boc,
    const float* __restrict__ xres,
    float* __restrict__ outF)
{
    __shared__ __align__(16) unsigned short Bl[64 * 256];   // 32 KB
    const int tid = threadIdx.x;
    const int wid = tid >> 6;
    const int lane = tid & 63;
    const int lo = lane & 15, hi = lane >> 4;
    const int m0 = blockIdx.x * 128 + wid * 32;
    const int n0 = blockIdx.y * 64;

#pragma unroll
    for (int j = 0; j < 8; ++j) {
        int chunkbase = (j * 4 + wid) * 64;
        int chunk = chunkbase + lane;
        int row = chunk >> 5, Jp = chunk & 31;
        int J = (Jp & 24) | ((Jp ^ row) & 7);
        GLD16(Wt + (n0 + row) * 256 + J * 8, Bl + chunkbase * 8);
    }
    asm volatile("s_waitcnt vmcnt(0)" ::: "memory");
    __syncthreads();

    const unsigned short* arow0 = A + (m0 + lo) * 256 + hi * 8;
    f32x4 acc[2][4] = {};
#pragma unroll
    for (int s = 0; s < 8; ++s) {
        bf16x8 a0 = *reinterpret_cast<const bf16x8*>(arow0 + s * 32);
        bf16x8 a1 = *reinterpret_cast<const bf16x8*>(arow0 + 16 * 256 + s * 32);
        int Jp = ((s >> 1) << 3) | ((((s & 1) << 2) + hi) ^ (lo & 7));
#pragma unroll
        for (int n = 0; n < 4; ++n) {
            bf16x8 b = *reinterpret_cast<const bf16x8*>(
                Bl + (n * 16 + lo) * 256 + Jp * 8);
            acc[0][n] = mfma16(a0, b, acc[0][n]);
            acc[1][n] = mfma16(a1, b, acc[1][n]);
        }
    }
#pragma unroll
    for (int mf = 0; mf < 2; ++mf) {
        const int row_base = m0 + mf * 16 + hi * 4;
#pragma unroll
        for (int n = 0; n < 4; ++n) {
            int gc = n0 + n * 16 + lo;
            float bs = boc[gc];
#pragma unroll
            for (int i = 0; i < 4; ++i)
                outF[(row_base + i) * 256 + gc] =
                    xres[(row_base + i) * 256 + gc] + acc[mf][n][i] + bs;
        }
    }
}

// ---------------------------------------------------------------------------
extern "C" void kernel_launch(void* const* d_in, const int* in_sizes, int n_in,
                              void* d_out, int out_size, void* d_ws, size_t ws_size,
                              hipStream_t stream) {
    const float* x  = (const float*)d_in[0];
    const float* Wq = (const float*)d_in[1];
    const float* bq = (const float*)d_in[2];
    const float* Wk = (const float*)d_in[3];
    const float* bk = (const float*)d_in[4];
    const float* Wv = (const float*)d_in[5];
    const float* bv = (const float*)d_in[6];
    const float* Wo = (const float*)d_in[7];
    const float* bo = (const float*)d_in[8];
    const float* Wc = (const float*)d_in[9];
    const float* bc = (const float*)d_in[10];
    float* out = (float*)d_out;

    char* p = (char*)d_ws;
    unsigned short* xbf  = (unsigned short*)p;  p += (size_t)MTOT * DMODEL * 2;   // 4 MB
    unsigned short* Wt   = (unsigned short*)p;  p += (size_t)1280 * 256 * 2;      // 640 KB
    float* bcat          = (float*)p;           p += (size_t)1280 * 4;            // 5 KB
    unsigned short* Qw   = (unsigned short*)p;  p += (size_t)32 * 2048 * 32 * 2;  // 4 MB
    unsigned short* Kw   = (unsigned short*)p;  p += (size_t)32 * 2048 * 32 * 2;  // 4 MB
    unsigned short* Vtw  = (unsigned short*)p;  p += (size_t)32 * 32 * 2048 * 2;  // 4 MB
    unsigned short* ctx  = (unsigned short*)p;  p += (size_t)MTOT * DMODEL * 2;   // 4 MB
    unsigned short* Woct = (unsigned short*)p;  p += (size_t)256 * 256 * 2;       // 128 KB
    float* bocf          = (float*)p;           p += (size_t)256 * 4;             // 1 KB

    // prep: 257 fold + 2048 xconv + 80 transpose + 5 bias = 2390 blocks
    prep_kernel<<<2390, 256, 0, stream>>>(x, Wq, Wk, Wv, Wo, Wc,
                                          bq, bk, bv, bo, bc,
                                          xbf, Wt, bcat, Woct, bocf);
    // QKV projection (Q pre-scaled by CSH; V stored key-permuted)
    gemm_qkv<<<dim3(64, 12), 256, 0, stream>>>(xbf, Wt, bcat, Qw, Kw, Vtw);
    // attention (KVBLK=64, 32KB LDS, 4 blocks/CU)
    attn_kernel<<<512, 256, 0, stream>>>(Qw, Kw, Vtw, ctx);
    // fused output+context projection + residual
    gemm_ctx<<<dim3(64, 4), 256, 0, stream>>>(ctx, Woct, bocf, x, out);
}

// Round 20
// 52.284 us; speedup vs baseline: 1.1702x; 1.1702x over previous
//
#include <hip/hip_runtime.h>

// Problem constants
#define DMODEL 256
#define HEADS 8
#define DHEAD 32
#define NSEQ 2048
#define BATCH 4
#define MTOT (BATCH*NSEQ)   // 8192

typedef __bf16 bf16x8 __attribute__((ext_vector_type(8)));
typedef float f32x4 __attribute__((ext_vector_type(4)));

// scale * log2(e) * 128: softmax_2(s*CS) computed via Schraudolph int exp2
// (bits16(2^y) ~= y + 16252 for y = s*CS*128; bias folded into QK MFMA C-in)
#define CSH 32.649321103346387f
// Schraudolph bias: 127<<7 = 16256, minus sigma 4.5 (minmax), plus 0.5 trunc
#define EXPC 16252.0f

__device__ __forceinline__ unsigned short f2bf(float f) {
    union { float f; unsigned int u; } v; v.f = f;
    unsigned int u = v.u;
    unsigned int r = u + 0x7FFFu + ((u >> 16) & 1u);   // RNE
    return (unsigned short)(r >> 16);
}

__device__ __forceinline__ unsigned pkbf(float a, float b) {
    union { __bf16 h[2]; unsigned u; } t;
    t.h[0] = (__bf16)a; t.h[1] = (__bf16)b;
    return t.u;
}

// packed Schraudolph exp2 finish: inputs already = score + EXPC (bias folded
// into the QK MFMA accumulator init). 2x v_cvt_i32_f32 + 1x v_perm_b32.
__device__ __forceinline__ unsigned pkexp(float a, float b) {
    int ia = (int)a;
    int ib = (int)b;
    return __builtin_amdgcn_perm((unsigned)ib, (unsigned)ia, 0x05040100u);
}

__device__ __forceinline__ f32x4 mfma16(bf16x8 a, bf16x8 b, f32x4 c) {
    return __builtin_amdgcn_mfma_f32_16x16x32_bf16(a, b, c, 0, 0, 0);
}

#define GLD16(g, l) __builtin_amdgcn_global_load_lds( \
    (const __attribute__((address_space(1))) unsigned int*)(g), \
    (__attribute__((address_space(3))) unsigned int*)(l), 16, 0, 0)

// ---------------------------------------------------------------------------
// prep (2390 blocks):
//  blocks 0..256    : Woc = Wo@Wc fold (row 256 = boc = bo@Wc + bc)
//  blocks 257..2304 : x -> bf16 (coalesced float4 -> ushort4)
//  blocks 2305..2384: tiled-coalesced weight transpose -> Wt[n][k] bf16
//  blocks 2385..2389: bias concat
// ---------------------------------------------------------------------------
__global__ __launch_bounds__(256) void prep_kernel(
    const float* __restrict__ x,
    const float* __restrict__ Wq, const float* __restrict__ Wk,
    const float* __restrict__ Wv, const float* __restrict__ Wo,
    const float* __restrict__ Wc,
    const float* __restrict__ bq, const float* __restrict__ bk,
    const float* __restrict__ bv, const float* __restrict__ bo,
    const float* __restrict__ bc,
    unsigned short* __restrict__ xbf,   // [8192][256]
    unsigned short* __restrict__ Wt,    // [1280][256]
    float* __restrict__ bcat,           // [1280]
    unsigned short* __restrict__ Woct,  // [256][256] = Woc^T bf16
    float* __restrict__ bocf)           // [256]
{
    const int tid = threadIdx.x;
    if (blockIdx.x < 257) {             // Woc / boc fold
        int k = blockIdx.x;             // 0..256
        int n = tid;                    // 0..255
        const float* arow = (k < 256) ? (Wo + k * 256) : bo;
        float a0 = 0.f, a1 = 0.f, a2 = 0.f, a3 = 0.f;
#pragma unroll 4
        for (int j = 0; j < 256; j += 4) {
            a0 = fmaf(arow[j],     Wc[j * 256 + n],       a0);
            a1 = fmaf(arow[j + 1], Wc[(j + 1) * 256 + n], a1);
            a2 = fmaf(arow[j + 2], Wc[(j + 2) * 256 + n], a2);
            a3 = fmaf(arow[j + 3], Wc[(j + 3) * 256 + n], a3);
        }
        float acc = (a0 + a1) + (a2 + a3);
        if (k < 256) Woct[n * 256 + k] = f2bf(acc);
        else         bocf[n] = acc + bc[n];
        return;
    }
    if (blockIdx.x < 2305) {            // x -> bf16
        int idx = (blockIdx.x - 257) * 256 + tid;     // < 524288
        float4 v = reinterpret_cast<const float4*>(x)[idx];
        ushort4 o;
        o.x = f2bf(v.x); o.y = f2bf(v.y); o.z = f2bf(v.z); o.w = f2bf(v.w);
        reinterpret_cast<ushort4*>(xbf)[idx] = o;
        return;
    }
    if (blockIdx.x < 2385) {            // transpose: 64n x 64k tile
        __shared__ unsigned short Lt[64 * 72];
        const int bb = blockIdx.x - 2305;
        const int wid = tid >> 6, lane = tid & 63;
        const int n0 = (bb >> 2) * 64, k0 = (bb & 3) * 64;
        const float* Wsrc; int col0;
        if (n0 < 256)       { Wsrc = Wq; col0 = n0; }
        else if (n0 < 512)  { Wsrc = Wk; col0 = n0 - 256; }
        else if (n0 < 768)  { Wsrc = Wv; col0 = n0 - 512; }
        else if (n0 < 1024) { Wsrc = Wo; col0 = n0 - 768; }
        else                { Wsrc = Wc; col0 = n0 - 1024; }
#pragma unroll
        for (int r = 0; r < 16; ++r) {
            int k = k0 + wid * 16 + r;
            Lt[lane * 72 + wid * 16 + r] = f2bf(Wsrc[k * 256 + col0 + lane]);
        }
        __syncthreads();
#pragma unroll
        for (int c = tid; c < 512; c += 256) {
            int row = c >> 3, seg = c & 7;
            *reinterpret_cast<bf16x8*>(Wt + (n0 + row) * 256 + k0 + seg * 8) =
                *reinterpret_cast<const bf16x8*>(Lt + row * 72 + seg * 8);
        }
        return;
    }
    int t = (blockIdx.x - 2385) * 256 + tid;   // bias concat
    if (t < 1280) {
        float v;
        if (t < 256)       v = bq[t];
        else if (t < 512)  v = bk[t - 256];
        else if (t < 768)  v = bv[t - 512];
        else if (t < 1024) v = bo[t - 768];
        else               v = bc[t - 1024];
        bcat[t] = v;
    }
}

// ---------------------------------------------------------------------------
// gemm_qkv: A = xbf (bf16). Wt staged in LDS (XOR-swizzled via pre-swizzled
// global_load_lds source). 32x64 per wave. LDS-bounce epilogue (b128 stores):
//   type 0/1 (Q/K): [128 m][72]; Q pre-scaled by CSH (= CS*128, Schraudolph).
//   type 2 (V): transposed [64 gc][136], stored KEY-PERMUTED:
//     pos0 = (nn&~63)|(nn&32)|((nn&8)<<1)|((nn&16)>>2) (two 8B writes).
// ---------------------------------------------------------------------------
__global__ __launch_bounds__(256) void gemm_qkv(
    const unsigned short* __restrict__ A,
    const unsigned short* __restrict__ Wt,
    const float* __restrict__ bias,
    unsigned short* __restrict__ outQ,
    unsigned short* __restrict__ outK,
    unsigned short* __restrict__ outVt)
{
    __shared__ __align__(16) unsigned short Bl[64 * 256];   // 32 KB
    const int tid = threadIdx.x;
    const int wid = tid >> 6;
    const int lane = tid & 63;
    const int lo = lane & 15, hi = lane >> 4;
    const int m0 = blockIdx.x * 128 + wid * 32;
    const int n0 = blockIdx.y * 64;

#pragma unroll
    for (int j = 0; j < 8; ++j) {
        int chunkbase = (j * 4 + wid) * 64;
        int chunk = chunkbase + lane;
        int row = chunk >> 5, Jp = chunk & 31;
        int J = (Jp & 24) | ((Jp ^ row) & 7);
        GLD16(Wt + (n0 + row) * 256 + J * 8, Bl + chunkbase * 8);
    }
    asm volatile("s_waitcnt vmcnt(0)" ::: "memory");
    __syncthreads();

    const unsigned short* arow0 = A + (m0 + lo) * 256 + hi * 8;
    f32x4 acc[2][4] = {};
#pragma unroll
    for (int s = 0; s < 8; ++s) {
        bf16x8 a0 = *reinterpret_cast<const bf16x8*>(arow0 + s * 32);
        bf16x8 a1 = *reinterpret_cast<const bf16x8*>(arow0 + 16 * 256 + s * 32);
        int Jp = ((s >> 1) << 3) | ((((s & 1) << 2) + hi) ^ (lo & 7));
#pragma unroll
        for (int n = 0; n < 4; ++n) {
            bf16x8 b = *reinterpret_cast<const bf16x8*>(
                Bl + (n * 16 + lo) * 256 + Jp * 8);
            acc[0][n] = mfma16(a0, b, acc[0][n]);
            acc[1][n] = mfma16(a1, b, acc[1][n]);
        }
    }

    // LDS-bounce epilogue
    const int type = blockIdx.y >> 2;     // 0:Q 1:K 2:V
    const int m0b = blockIdx.x * 128;
    unsigned short* Lb = Bl;
    __syncthreads();
    if (type < 2) {                       // [128][72]
#pragma unroll
        for (int mf = 0; mf < 2; ++mf)
#pragma unroll
        for (int n = 0; n < 4; ++n) {
            float bs = bias[n0 + n * 16 + lo];
#pragma unroll
            for (int i = 0; i < 4; ++i) {
                float val = acc[mf][n][i] + bs;
                if (type == 0) val *= CSH;
                Lb[(wid * 32 + mf * 16 + hi * 4 + i) * 72 + n * 16 + lo] = f2bf(val);
            }
        }
    } else {                              // transposed [64][136]
#pragma unroll
        for (int mf = 0; mf < 2; ++mf)
#pragma unroll
        for (int n = 0; n < 4; ++n) {
            float bs = bias[n0 + n * 16 + lo];
            uint2 pk;
            pk.x = pkbf(acc[mf][n][0] + bs, acc[mf][n][1] + bs);
            pk.y = pkbf(acc[mf][n][2] + bs, acc[mf][n][3] + bs);
            *reinterpret_cast<uint2*>(
                Lb + (n * 16 + lo) * 136 + wid * 32 + mf * 16 + hi * 4) = pk;
        }
    }
    __syncthreads();
    if (type < 2) {
        unsigned short* outP = (type == 0) ? outQ : outK;
#pragma unroll
        for (int r = 0; r < 4; ++r) {
            int cid = r * 256 + tid;
            int m_l = cid >> 3, seg = cid & 7;
            bf16x8 chunk = *reinterpret_cast<const bf16x8*>(Lb + m_l * 72 + seg * 8);
            int m = m0b + m_l, gc = n0 + seg * 8;
            int b = m >> 11, nn = m & 2047, hh = (gc >> 5) & 7, dh = gc & 31;
            *reinterpret_cast<bf16x8*>(
                outP + (((b * 8) + hh) * 2048 + nn) * 32 + dh) = chunk;
        }
    } else {
#pragma unroll
        for (int r = 0; r < 4; ++r) {
            int cid = r * 256 + tid;
            int gcl = cid >> 4, seg = cid & 15;
            const unsigned short* src = Lb + gcl * 136 + seg * 8;
            uint2 lo4 = *reinterpret_cast<const uint2*>(src);
            uint2 hi4 = *reinterpret_cast<const uint2*>(src + 4);
            int gc = n0 + gcl, m = m0b + seg * 8;
            int b = m >> 11, nn = m & 2047, hh = (gc >> 5) & 7, dh = gc & 31;
            int pos0 = (nn & ~63) | (nn & 32) | ((nn & 8) << 1) | ((nn & 16) >> 2);
            unsigned short* dst = outVt + (((b * 8) + hh) * 32 + dh) * 2048;
            *reinterpret_cast<uint2*>(dst + pos0)     = lo4;
            *reinterpret_cast<uint2*>(dst + pos0 + 8) = hi4;
        }
    }
}

// ---------------------------------------------------------------------------
// Flash attention (R18 config — session best): 64 q-rows/wave in 4 groups,
// split-KV (2 qsub x 2 half), 512 blocks, KVBLK=128, 64KB LDS dbuf.
// Schraudolph bias folded into the QK MFMA accumulator init (C-in = EXPC);
// softmax finish = 2x v_cvt_i32 + 1x v_perm per 2 scores.
// Lane-local PV B-frags (V key-permuted); denom via ones-MFMA.
// ---------------------------------------------------------------------------
__global__ __launch_bounds__(256, 2) void attn_kernel(
    const unsigned short* __restrict__ Q,    // [32][2048][32] bf16 (pre-scaled CSH)
    const unsigned short* __restrict__ K,    // [32][2048][32] bf16
    const unsigned short* __restrict__ Vt,   // [32][32][2048] bf16 (permuted)
    unsigned short* __restrict__ ctx)        // [8192][256] bf16 (heads merged)
{
    // K: [half][buf] @ half*16384 + buf*8192 ; V same @ +32768. 64 KB.
    __shared__ __align__(16) char smem[65536];

    const int tid = threadIdx.x;
    const int wid = tid >> 6;          // 0..3
    const int lane = tid & 63;
    const int lo = lane & 15, hi = lane >> 4;
    const int qsub = wid & 1;
    const int half = wid >> 1;

    // XCD swizzle: bid = 8*(qt + 16*g) + r ; bh = g*8+r
    const int bid = blockIdx.x;
    const int bh = ((bid >> 7) << 3) | (bid & 7);
    const int qt = (bid >> 3) & 15;
    const int q0 = qt * 128 + qsub * 64;

    const unsigned short* Qb = Q + bh * (NSEQ * 32);
    const unsigned short* Kh0 = K + bh * (NSEQ * 32) + (half * 1024) * 32;
    const unsigned short* Vh0 = Vt + bh * (32 * NSEQ) + half * 1024;

    bf16x8 qf[4];
#pragma unroll
    for (int g = 0; g < 4; ++g)
        qf[g] = *reinterpret_cast<const bf16x8*>(
            Qb + (q0 + g * 16 + lo) * 32 + hi * 8);

    // staging: 128 threads per half, 8 GLD16 per thread per 128-key tile
    const int lt2 = tid & 127;
    const int cA = lt2, cB = lt2 + 128;
    const unsigned short* kA0 = Kh0 + (2 * (cA >> 3) + ((cA >> 2) & 1)) * 32
                                    + ((cA & 3) ^ ((cA >> 3) & 3)) * 8;
    const unsigned short* kA1 = Kh0 + (2 * (cB >> 3) + ((cB >> 2) & 1)) * 32
                                    + ((cB & 3) ^ ((cB >> 3) & 3)) * 8;
    const unsigned short* vA0 = Vh0 + (cA >> 3) * NSEQ
                                    + ((cA & 7) ^ ((cA >> 3) & 7)) * 8;
    const unsigned short* vA1 = Vh0 + (cB >> 3) * NSEQ
                                    + ((cB & 7) ^ ((cB >> 3) & 7)) * 8;
    char* kd0 = smem + half * 16384 + lt2 * 16;
    char* kd1 = kd0 + 2048;
    char* vd0 = smem + 32768 + half * 16384 + lt2 * 16;
    char* vd1 = vd0 + 2048;

    f32x4 o0[4] = {}, o1[4] = {}, od[4] = {};
    const f32x4 ec = {EXPC, EXPC, EXPC, EXPC};   // Schraudolph bias as C-in
    const int prs = lo & 7;
    const int kxor = (hi ^ ((lo >> 1) & 3)) * 8;

    union { unsigned u[4]; bf16x8 v; } ones;
    ones.u[0] = 0x3F803F80u; ones.u[1] = 0x3F803F80u;
    ones.u[2] = 0x3F803F80u; ones.u[3] = 0x3F803F80u;

#define STAGE_T(tt, buf) do { \
    GLD16(kA0 + (tt) * 4096,        kd0 + (buf) * 8192); \
    GLD16(kA0 + (tt) * 4096 + 2048, kd0 + (buf) * 8192 + 4096); \
    GLD16(kA1 + (tt) * 4096,        kd1 + (buf) * 8192); \
    GLD16(kA1 + (tt) * 4096 + 2048, kd1 + (buf) * 8192 + 4096); \
    GLD16(vA0 + (tt) * 128,         vd0 + (buf) * 8192); \
    GLD16(vA0 + (tt) * 128 + 64,    vd0 + (buf) * 8192 + 4096); \
    GLD16(vA1 + (tt) * 128,         vd1 + (buf) * 8192); \
    GLD16(vA1 + (tt) * 128 + 64,    vd1 + (buf) * 8192 + 4096); \
} while (0)

    STAGE_T(0, 0);
    asm volatile("s_waitcnt vmcnt(0)" ::: "memory");
    __builtin_amdgcn_s_barrier();
    __builtin_amdgcn_sched_barrier(0);

    int cur = 0;
    for (int t = 0; t < 8; ++t) {
        if (t < 7) STAGE_T(t + 1, cur ^ 1);
        const unsigned short* Kc =
            (const unsigned short*)(smem + half * 16384 + cur * 8192);
        const unsigned short* Vc =
            (const unsigned short*)(smem + 32768 + half * 16384 + cur * 8192);

        __builtin_amdgcn_s_setprio(1);
#pragma unroll
        for (int h2 = 0; h2 < 2; ++h2) {     // 64-key sub-tiles
            const unsigned short* Kh = Kc + h2 * 2048;
            const unsigned short* Vh = Vc + h2 * 2048;
            f32x4 s[4][4];
#pragma unroll
            for (int c = 0; c < 4; ++c) {
                bf16x8 kf = *reinterpret_cast<const bf16x8*>(
                    Kh + (c * 16 + lo) * 32 + kxor);
#pragma unroll
                for (int g = 0; g < 4; ++g)
                    s[g][c] = mfma16(kf, qf[g], ec);   // bias folded in
            }
#pragma unroll
            for (int kk = 0; kk < 2; ++kk) {
                int sw = ((4 * kk + hi) ^ prs) * 8;
                bf16x8 a0 = *reinterpret_cast<const bf16x8*>(Vh + lo * 64 + sw);
                bf16x8 a1 = *reinterpret_cast<const bf16x8*>(Vh + (16 + lo) * 64 + sw);
#pragma unroll
                for (int g = 0; g < 4; ++g) {
                    const f32x4 s0 = s[g][2 * kk], s1 = s[g][2 * kk + 1];
                    union { unsigned u[4]; bf16x8 v; } pb;
                    pb.u[0] = pkexp(s0[0], s0[1]);
                    pb.u[1] = pkexp(s0[2], s0[3]);
                    pb.u[2] = pkexp(s1[0], s1[1]);
                    pb.u[3] = pkexp(s1[2], s1[3]);
                    o0[g] = mfma16(a0, pb.v, o0[g]);
                    o1[g] = mfma16(a1, pb.v, o1[g]);
                    od[g] = mfma16(ones.v, pb.v, od[g]);
                }
            }
        }
        __builtin_amdgcn_s_setprio(0);

        if (t < 7) {
            asm volatile("s_waitcnt vmcnt(0)" ::: "memory");
            __builtin_amdgcn_s_barrier();
            __builtin_amdgcn_sched_barrier(0);
            cur ^= 1;
        }
    }

    // combine halves (pure addition; no-max softmax partials)
    float* comb = (float*)smem;                 // [2][64][48]
    const int cidx = (qsub * 64 + lane) * 48;
    __syncthreads();
    if (half) {
#pragma unroll
        for (int g = 0; g < 4; ++g) {
            *reinterpret_cast<f32x4*>(comb + cidx + g * 12)     = o0[g];
            *reinterpret_cast<f32x4*>(comb + cidx + g * 12 + 4) = o1[g];
            comb[cidx + g * 12 + 8] = od[g][0];
        }
    }
    __syncthreads();
    if (!half) {
        const int b = bh >> 3, h = bh & 7;
#pragma unroll
        for (int g = 0; g < 4; ++g) {
            f32x4 p0 = *reinterpret_cast<const f32x4*>(comb + cidx + g * 12);
            f32x4 p1 = *reinterpret_cast<const f32x4*>(comb + cidx + g * 12 + 4);
            float inv = 1.0f / (od[g][0] + comb[cidx + g * 12 + 8]);
            f32x4 r0 = o0[g] + p0, r1 = o1[g] + p1;
            unsigned short* dst = ctx
                + (size_t)((b * 2048 + q0 + g * 16 + lo)) * 256 + h * 32;
            ushort4 w0, w1;
            w0.x = f2bf(r0[0] * inv); w0.y = f2bf(r0[1] * inv);
            w0.z = f2bf(r0[2] * inv); w0.w = f2bf(r0[3] * inv);
            w1.x = f2bf(r1[0] * inv); w1.y = f2bf(r1[1] * inv);
            w1.z = f2bf(r1[2] * inv); w1.w = f2bf(r1[3] * inv);
            *reinterpret_cast<ushort4*>(dst + hi * 4)      = w0;
            *reinterpret_cast<ushort4*>(dst + 16 + hi * 4) = w1;
        }
    }
#undef STAGE_T
}

// ---------------------------------------------------------------------------
// gemm_ctx: out = x + ctx @ Woc + boc. A = ctx bf16 direct; B = Woct staged
// in LDS (swizzled). 32 rows x 64 cols / wave.
// ---------------------------------------------------------------------------
__global__ __launch_bounds__(256) void gemm_ctx(
    const unsigned short* __restrict__ A,
    const unsigned short* __restrict__ Wt,
    const float* __restrict__ boc,
    const float* __restrict__ xres,
    float* __restrict__ outF)
{
    __shared__ __align__(16) unsigned short Bl[64 * 256];   // 32 KB
    const int tid = threadIdx.x;
    const int wid = tid >> 6;
    const int lane = tid & 63;
    const int lo = lane & 15, hi = lane >> 4;
    const int m0 = blockIdx.x * 128 + wid * 32;
    const int n0 = blockIdx.y * 64;

#pragma unroll
    for (int j = 0; j < 8; ++j) {
        int chunkbase = (j * 4 + wid) * 64;
        int chunk = chunkbase + lane;
        int row = chunk >> 5, Jp = chunk & 31;
        int J = (Jp & 24) | ((Jp ^ row) & 7);
        GLD16(Wt + (n0 + row) * 256 + J * 8, Bl + chunkbase * 8);
    }
    asm volatile("s_waitcnt vmcnt(0)" ::: "memory");
    __syncthreads();

    const unsigned short* arow0 = A + (m0 + lo) * 256 + hi * 8;
    f32x4 acc[2][4] = {};
#pragma unroll
    for (int s = 0; s < 8; ++s) {
        bf16x8 a0 = *reinterpret_cast<const bf16x8*>(arow0 + s * 32);
        bf16x8 a1 = *reinterpret_cast<const bf16x8*>(arow0 + 16 * 256 + s * 32);
        int Jp = ((s >> 1) << 3) | ((((s & 1) << 2) + hi) ^ (lo & 7));
#pragma unroll
        for (int n = 0; n < 4; ++n) {
            bf16x8 b = *reinterpret_cast<const bf16x8*>(
                Bl + (n * 16 + lo) * 256 + Jp * 8);
            acc[0][n] = mfma16(a0, b, acc[0][n]);
            acc[1][n] = mfma16(a1, b, acc[1][n]);
        }
    }
#pragma unroll
    for (int mf = 0; mf < 2; ++mf) {
        const int row_base = m0 + mf * 16 + hi * 4;
#pragma unroll
        for (int n = 0; n < 4; ++n) {
            int gc = n0 + n * 16 + lo;
            float bs = boc[gc];
#pragma unroll
            for (int i = 0; i < 4; ++i)
                outF[(row_base + i) * 256 + gc] =
                    xres[(row_base + i) * 256 + gc] + acc[mf][n][i] + bs;
        }
    }
}

// ---------------------------------------------------------------------------
extern "C" void kernel_launch(void* const* d_in, const int* in_sizes, int n_in,
                              void* d_out, int out_size, void* d_ws, size_t ws_size,
                              hipStream_t stream) {
    const float* x  = (const float*)d_in[0];
    const float* Wq = (const float*)d_in[1];
    const float* bq = (const float*)d_in[2];
    const float* Wk = (const float*)d_in[3];
    const float* bk = (const float*)d_in[4];
    const float* Wv = (const float*)d_in[5];
    const float* bv = (const float*)d_in[6];
    const float* Wo = (const float*)d_in[7];
    const float* bo = (const float*)d_in[8];
    const float* Wc = (const float*)d_in[9];
    const float* bc = (const float*)d_in[10];
    float* out = (float*)d_out;

    char* p = (char*)d_ws;
    unsigned short* xbf  = (unsigned short*)p;  p += (size_t)MTOT * DMODEL * 2;   // 4 MB
    unsigned short* Wt   = (unsigned short*)p;  p += (size_t)1280 * 256 * 2;      // 640 KB
    float* bcat          = (float*)p;           p += (size_t)1280 * 4;            // 5 KB
    unsigned short* Qw   = (unsigned short*)p;  p += (size_t)32 * 2048 * 32 * 2;  // 4 MB
    unsigned short* Kw   = (unsigned short*)p;  p += (size_t)32 * 2048 * 32 * 2;  // 4 MB
    unsigned short* Vtw  = (unsigned short*)p;  p += (size_t)32 * 32 * 2048 * 2;  // 4 MB
    unsigned short* ctx  = (unsigned short*)p;  p += (size_t)MTOT * DMODEL * 2;   // 4 MB
    unsigned short* Woct = (unsigned short*)p;  p += (size_t)256 * 256 * 2;       // 128 KB
    float* bocf          = (float*)p;           p += (size_t)256 * 4;             // 1 KB

    // prep: 257 fold + 2048 xconv + 80 transpose + 5 bias = 2390 blocks
    prep_kernel<<<2390, 256, 0, stream>>>(x, Wq, Wk, Wv, Wo, Wc,
                                          bq, bk, bv, bo, bc,
                                          xbf, Wt, bcat, Woct, bocf);
    // QKV projection (Q pre-scaled by CSH; V stored key-permuted)
    gemm_qkv<<<dim3(64, 12), 256, 0, stream>>>(xbf, Wt, bcat, Qw, Kw, Vtw);
    // attention (R18 config: KVBLK=128, 64KB LDS, 2 blocks/CU)
    attn_kernel<<<512, 256, 0, stream>>>(Qw, Kw, Vtw, ctx);
    // fused output+context projection + residual
    gemm_ctx<<<dim3(64, 4), 256, 0, stream>>>(ctx, Woct, bocf, x, out);
}